// Round 16
// baseline (319.027 us; speedup 1.0000x reference)
//
#include <hip/hip_runtime.h>

// SNNConv2d — bit-exact XLA-CPU fp32 replication (verified r6/r8/r10-r14).
// FROZEN: per output element, acc folds taps ascending (kh,kw,ci) with
// single-rounded fp32 FMA; membrane = (mem+c)*0.9f (two rounded ops);
// spike = mem >= 0.25f; exact reset; OOB taps = exact-zero products.
//
// r15: (1) inline-asm v_pk_fma_f32 (2 independent chains/instr, SGPR-pair
// weight operand) — halves FMA issue. (2) straight-line 9-tap software
// pipeline: tap m+1's 16 x-loads issue before tap m's FMA burst (ping-pong
// xv0/xv1, all indices static). Boundary taps branchless via clamp+mask
// (exact-zero product = fma identity; acc never becomes -0 in RN).

#define BB   8
#define CIN  16
#define HH   64
#define WW   64
#define TT   32
#define COUT 32
#define HWT  (HH * WW * TT)

typedef float f32x2 __attribute__((ext_vector_type(2)));

// wT[tau][co], tau = (kh*3+kw)*16 + ci
__global__ void repack_w(const float* __restrict__ wgt, float* __restrict__ wT) {
    const int e = blockIdx.x * 256 + threadIdx.x;
    if (e < 144 * 32) {
        const int co  = e & 31;
        const int tau = e >> 5;
        const int ci  = tau & 15;
        const int khw = tau >> 4;
        wT[tau * 32 + co] = wgt[co * 144 + ci * 9 + khw];
    }
}

// load tap M's 16 ci values into XV (clamped addr, exact-zero mask)
#define LOADTAP(M, XV)                                                      \
    {                                                                       \
        const int kh = (M) / 3, kw = (M) % 3;                               \
        const int hs = h + kh - 1;                                          \
        const int ws = w + kw - 1;                                          \
        const bool okh = (unsigned)hs < HH;                                 \
        const bool okw = (unsigned)ws < WW;                                 \
        const int hsc = okh ? hs : 0;                                       \
        const int wsc = okw ? ws : 0;                                       \
        const float* xp = x + ((b * CIN * HH + hsc) * WW + wsc) * TT + t;   \
        _Pragma("unroll")                                                   \
        for (int ci = 0; ci < CIN; ++ci) XV[ci] = xp[ci * HWT];             \
        const bool ok = okh && okw;                                         \
        _Pragma("unroll")                                                   \
        for (int ci = 0; ci < CIN; ++ci) XV[ci] = ok ? XV[ci] : 0.0f;       \
    }

// fold tap M from XV into acc2 — (kh,kw,ci)-ascending, v_pk_fma_f32
#define FMATAP(M, XV)                                                       \
    {                                                                       \
        const f32x2* wr2 = (const f32x2*)(wT + (M) * (CIN * 32));           \
        _Pragma("unroll")                                                   \
        for (int ci = 0; ci < CIN; ++ci) {                                  \
            const f32x2 xv2 = {XV[ci], XV[ci]};                             \
            _Pragma("unroll")                                               \
            for (int c2 = 0; c2 < 16; ++c2) {                               \
                const f32x2 wv = wr2[ci * 16 + c2];                         \
                asm("v_pk_fma_f32 %0, %1, %2, %0"                           \
                    : "+v"(acc2[c2])                                        \
                    : "v"(xv2), "s"(wv));                                   \
            }                                                               \
        }                                                                   \
    }

__global__ __launch_bounds__(256, 4)
void snn_main(const float* __restrict__ x, const float* __restrict__ wT,
              float* __restrict__ out) {
    // XCD-chunk swizzle: XCD k owns work chunk [k*512,(k+1)*512) = image b=k.
    const int wk = (blockIdx.x & 7) * 512 + (blockIdx.x >> 3);
    const int b  = wk >> 9;
    const int h  = (wk >> 3) & 63;
    const int w0 = (wk & 7) * 8;

    const int tid = threadIdx.x;
    const int t   = tid & 31;          // time on lanes
    const int wi  = tid >> 5;          // 0..7
    const int w   = w0 + wi;

    f32x2 acc2[16];                     // acc2[i] = {acc[2i], acc[2i+1]}
#pragma unroll
    for (int i = 0; i < 16; ++i) acc2[i] = (f32x2){0.0f, 0.0f};

    float xv0[16], xv1[16];

    // ---- 9-tap software pipeline; fold order (kh,kw,ci) — FROZEN ----
    LOADTAP(0, xv0)
    LOADTAP(1, xv1)  FMATAP(0, xv0)
    LOADTAP(2, xv0)  FMATAP(1, xv1)
    LOADTAP(3, xv1)  FMATAP(2, xv0)
    LOADTAP(4, xv0)  FMATAP(3, xv1)
    LOADTAP(5, xv1)  FMATAP(4, xv0)
    LOADTAP(6, xv0)  FMATAP(5, xv1)
    LOADTAP(7, xv1)  FMATAP(6, xv0)
    LOADTAP(8, xv0)  FMATAP(7, xv1)
                     FMATAP(8, xv0)

    // ---- two-pass LDS transpose + membrane scan (18432 B) ----
    __shared__ float s_tr[128 * 36];
#pragma unroll
    for (int p = 0; p < 2; ++p) {
        if (p) __syncthreads();                        // pass-1 reads done
#pragma unroll
        for (int j = 0; j < 16; ++j) {                 // write co = 16p+j
            const int c = 16 * p + j;
            s_tr[(j * 8 + wi) * 36 + t] = acc2[c >> 1][c & 1];
        }
        __syncthreads();
        if (tid < 128) {
            const int j2  = tid >> 3;                  // 0..15
            const int wi2 = tid & 7;
            const int co2 = 16 * p + j2;
            const float* rr = s_tr + tid * 36;
            float* op = out + (((b * COUT + co2) * HH + h) * WW + (w0 + wi2)) * TT;
            float mem = 0.0f;
#pragma unroll
            for (int t4 = 0; t4 < TT; t4 += 4) {
                const float4 q = *reinterpret_cast<const float4*>(rr + t4);
                const float cv[4] = {q.x, q.y, q.z, q.w};
                float4 o;
                float* vp = &o.x;
#pragma unroll
                for (int jj = 0; jj < 4; ++jj) {
                    mem = (mem + cv[jj]) * 0.9f;       // two rounded ops — FROZEN
                    const bool sp = (mem >= 0.25f);
                    vp[jj] = sp ? 1.0f : 0.0f;
                    if (sp) mem = 0.0f;
                }
                *reinterpret_cast<float4*>(op + t4) = o;
            }
        }
    }
}

extern "C" void kernel_launch(void* const* d_in, const int* in_sizes, int n_in,
                              void* d_out, int out_size, void* d_ws, size_t ws_size,
                              hipStream_t stream) {
    const float* x   = (const float*)d_in[0];   // 8*16*64*64*32
    const float* wgt = (const float*)d_in[1];   // 32*16*3*3
    float* out = (float*)d_out;                 // 8*32*64*64*32
    float* wT  = (float*)d_ws;                  // 144*32 f32 = 18432 B scratch

    repack_w<<<18, 256, 0, stream>>>(wgt, wT);

    snn_main<<<dim3(4096), dim3(256), 0, stream>>>(x, wT, out);
}